// Round 1
// baseline (112.041 us; speedup 1.0000x reference)
//
#include <hip/hip_runtime.h>
#include <hip/hip_cooperative_groups.h>

namespace cg = cooperative_groups;

// KDPointToPointLoss: B=8, C=3, N=M=4096, fp32.
// loss[b] = (1/(3N)) * sum_n [ s_n^2 + min_m (t_m^2 - 2 s_n . t_m) ]
//
// R6: fused single cooperative kernel. Phase 1 (unchanged from R5, already
// at its ~6-7us VALU floor: 3 fma + min3/2 per pair, LDS broadcast reads
// overlap on the LDS pipe): 512 blocks = 8 batches x 8 target-eighths x
// 8 source-groups; wave sweeps 64 staged targets vs 512 sources (8/lane).
// grid.sync(), then phase 2 on blocks 0..63: per-source min over the 8
// eighths (64-way parallel vs old 8-block reduce_kernel), block-sum, one
// atomicAdd per block into out[b] (zero-inited before the sync).
// Saves one kernel dispatch + gap and ~6us of reduce time. The remaining
// ~40us top dispatch is the harness's 256 MiB workspace poison fill.

#define B_ 8
#define N_ 4096
#define CH 4096
#define BS 12288
#define TQ 512           // targets per block
#define BIG 3.4e38f

__global__ __launch_bounds__(512, 8)    // 8 waves/EU -> 4 blocks/CU, VGPR<=64
void nn_loss_fused(const float* __restrict__ src,
                   const float* __restrict__ tgt,
                   float* __restrict__ partial,
                   float* __restrict__ out) {
    __shared__ __align__(16) char smem[8 * TQ * 4];   // 16 KB: stage(8K), red(16K)
    float4* stage = (float4*)smem;
    float*  red   = (float*)smem;

    const int tid  = threadIdx.x;        // 0..511
    const int blk  = blockIdx.x;
    const int b    = blk >> 6;           // 0..7
    const int e    = (blk >> 3) & 7;     // target eighth 0..7
    const int sgrp = blk & 7;            // source group 0..7 (512 srcs each)
    const int ls   = tid & 63;
    const int w    = tid >> 6;           // wave 0..7

    // zero output accumulators; visible to phase-2 atomics after grid.sync
    if (blk == 0 && tid < B_) out[tid] = 0.0f;

    // ---- stage this eighth's targets: (x,y,z, x^2+y^2+z^2) ----
    {
        const float* tb = tgt + b * BS;
        const int m = (e << 9) + tid;
        float x = tb[m], y = tb[m + CH], z = tb[m + 2 * CH];
        stage[tid] = make_float4(x, y, z, x * x + y * y + z * z);
    }

    // ---- load 8 sources per lane (store -2*coords; s^2 recomputed later) ----
    const float* sb = src + b * BS;
    float ax[8], ay[8], az[8];
    #pragma unroll
    for (int j = 0; j < 8; ++j) {
        int n = (sgrp << 9) + (j << 6) + ls;
        ax[j] = -2.0f * sb[n];
        ay[j] = -2.0f * sb[n + CH];
        az[j] = -2.0f * sb[n + 2 * CH];
    }

    __syncthreads();

    // ---- sweep this wave's 64 targets against 512 sources ----
    float best[8];
    #pragma unroll
    for (int j = 0; j < 8; ++j) best[j] = BIG;

    const float4* tp = stage + (w << 6);
    #pragma unroll 2
    for (int i = 0; i < 64; i += 2) {
        float4 t0 = tp[i];
        float4 t1 = tp[i + 1];
        #pragma unroll
        for (int j = 0; j < 8; ++j) {
            float d0 = fmaf(ax[j], t0.x, fmaf(ay[j], t0.y, fmaf(az[j], t0.z, t0.w)));
            float d1 = fmaf(ax[j], t1.x, fmaf(ay[j], t1.y, fmaf(az[j], t1.z, t1.w)));
            best[j] = fminf(fminf(best[j], d0), d1);   // v_min3_f32
        }
    }

    __syncthreads();   // staging reads done; reuse smem as red[8][512]

    // store best + s^2  (s^2 = 0.25*(ax^2+ay^2+az^2), exact pow2 scale)
    #pragma unroll
    for (int j = 0; j < 8; ++j) {
        float s2 = 0.25f * fmaf(ax[j], ax[j], fmaf(ay[j], ay[j], az[j] * az[j]));
        red[(w << 9) + (j << 6) + ls] = best[j] + s2;
    }

    __syncthreads();

    // combine across 8 waves; thread tid handles source sgrp*512+tid
    float mn = red[tid];
    #pragma unroll
    for (int v = 1; v < 8; ++v)
        mn = fminf(mn, red[(v << 9) + tid]);
    partial[(e << 15) + (b << 12) + (sgrp << 9) + tid] = mn;

    // ---- grid-wide sync, then 64-block parallel reduce ----
    cg::this_grid().sync();

    if (blk < 64) {
        const int b2 = blk >> 3;             // batch
        const int g2 = blk & 7;              // source group
        const int base = (b2 << 12) + (g2 << 9) + tid;
        float v0 = partial[base];
        #pragma unroll
        for (int e2 = 1; e2 < 8; ++e2)
            v0 = fminf(v0, partial[(e2 << 15) + base]);

        #pragma unroll
        for (int off = 32; off > 0; off >>= 1)
            v0 += __shfl_down(v0, off, 64);

        // red[] safely reusable: all block threads passed grid.sync
        if (ls == 0) red[w] = v0;
        __syncthreads();
        if (tid == 0) {
            float s = 0.0f;
            #pragma unroll
            for (int k = 0; k < 8; ++k) s += red[k];
            atomicAdd(&out[b2], s * (1.0f / (3.0f * (float)N_)));
        }
    }
}

extern "C" void kernel_launch(void* const* d_in, const int* in_sizes, int n_in,
                              void* d_out, int out_size, void* d_ws, size_t ws_size,
                              hipStream_t stream) {
    const float* src = (const float*)d_in[0];   // [8,3,4096]
    const float* tgt = (const float*)d_in[1];   // [8,3,4096]
    float* out = (float*)d_out;                 // [8]
    float* partial = (float*)d_ws;              // 8*8*4096 floats = 1 MB

    void* args[] = {(void*)&src, (void*)&tgt, (void*)&partial, (void*)&out};
    hipLaunchCooperativeKernel(reinterpret_cast<void*>(nn_loss_fused),
                               dim3(512), dim3(512), args, 0, stream);
}

// Round 2
// 69.997 us; speedup vs baseline: 1.6006x; 1.6006x over previous
//
#include <hip/hip_runtime.h>

// KDPointToPointLoss: B=8, C=3, N=M=4096, fp32.
// loss[b] = (1/(3N)) * sum_n [ s_n^2 + min_m (t_m^2 - 2 s_n . t_m) ]
//
// R7: revert cooperative fusion (grid.sync spin cost ~35us, measured R6:
// fused kernel 46.5us with VALUBusy 24.8% => ~35us idle). Back to two
// dispatches, with two fixes over R5 (68.6us):
//  - main: 1024 blocks (8 batches x 16 target-16ths x 8 src-groups),
//    TQ=256. Same 8-src/lane VALU:LDS ratio (VALU-bound: 15.4K cyc VALU
//    vs 12.3K cyc LDS per CU), but 4 blocks/CU = 32 waves/CU (R5 ran
//    2 blocks/CU = 16 waves) to hide ds_read->FMA latency + staging.
//  - reduce: 64 blocks (vs 8) + atomicAdd into memset-zeroed out[].
// Remaining ~40us top dispatch is the harness's 256 MiB poison fill.

#define B_ 8
#define N_ 4096
#define CH 4096
#define BS 12288
#define TQ 256           // targets per block (one sixteenth per e)
#define NE 16            // target sixteenths
#define BIG 3.4e38f

__global__ __launch_bounds__(512, 8)    // 8 waves/EU -> 4 blocks/CU, VGPR<=64
void nn_loss_main(const float* __restrict__ src,
                  const float* __restrict__ tgt,
                  float* __restrict__ partial) {
    __shared__ __align__(16) char smem[8 * 512 * 4];   // 16 KB: stage(4K), red(16K)
    float4* stage = (float4*)smem;
    float*  red   = (float*)smem;

    const int tid  = threadIdx.x;        // 0..511
    const int blk  = blockIdx.x;         // 0..1023
    const int b    = blk >> 7;           // 0..7
    const int e    = (blk >> 3) & 15;    // target sixteenth 0..15
    const int sgrp = blk & 7;            // source group 0..7 (512 srcs each)
    const int ls   = tid & 63;
    const int w    = tid >> 6;           // wave 0..7

    // ---- stage this sixteenth's targets: (x,y,z, x^2+y^2+z^2) ----
    if (tid < TQ) {
        const float* tb = tgt + b * BS;
        const int m = (e << 8) + tid;
        float x = tb[m], y = tb[m + CH], z = tb[m + 2 * CH];
        stage[tid] = make_float4(x, y, z, x * x + y * y + z * z);
    }

    // ---- load 8 sources per lane (store -2*coords; s^2 recomputed later) ----
    const float* sb = src + b * BS;
    float ax[8], ay[8], az[8];
    #pragma unroll
    for (int j = 0; j < 8; ++j) {
        int n = (sgrp << 9) + (j << 6) + ls;
        ax[j] = -2.0f * sb[n];
        ay[j] = -2.0f * sb[n + CH];
        az[j] = -2.0f * sb[n + 2 * CH];
    }

    __syncthreads();

    // ---- sweep this wave's 32 targets against 512 sources ----
    float best[8];
    #pragma unroll
    for (int j = 0; j < 8; ++j) best[j] = BIG;

    const float4* tp = stage + (w << 5);
    #pragma unroll 2
    for (int i = 0; i < 32; i += 2) {
        float4 t0 = tp[i];
        float4 t1 = tp[i + 1];
        #pragma unroll
        for (int j = 0; j < 8; ++j) {
            float d0 = fmaf(ax[j], t0.x, fmaf(ay[j], t0.y, fmaf(az[j], t0.z, t0.w)));
            float d1 = fmaf(ax[j], t1.x, fmaf(ay[j], t1.y, fmaf(az[j], t1.z, t1.w)));
            best[j] = fminf(fminf(best[j], d0), d1);   // v_min3_f32
        }
    }

    __syncthreads();   // staging reads done; reuse smem as red[8][512]

    // store best + s^2  (s^2 = 0.25*(ax^2+ay^2+az^2), exact pow2 scale)
    #pragma unroll
    for (int j = 0; j < 8; ++j) {
        float s2 = 0.25f * fmaf(ax[j], ax[j], fmaf(ay[j], ay[j], az[j] * az[j]));
        red[(w << 9) + (j << 6) + ls] = best[j] + s2;
    }

    __syncthreads();

    // combine across 8 waves; thread tid handles source sgrp*512+tid
    float mn = red[tid];
    #pragma unroll
    for (int v = 1; v < 8; ++v)
        mn = fminf(mn, red[(v << 9) + tid]);
    partial[(e << 15) + (b << 12) + (sgrp << 9) + tid] = mn;
}

// ---- pass 2: min over 16 sixteenths per source, sum per batch ----
// 64 blocks = 8 batches x 8 source-chunks; atomicAdd into zeroed out[].
__global__ __launch_bounds__(512)
void reduce_kernel(const float* __restrict__ partial,
                   float* __restrict__ out) {
    const int blk = blockIdx.x;          // 0..63
    const int b   = blk >> 3;            // batch
    const int g   = blk & 7;             // source chunk of 512
    const int tid = threadIdx.x;         // 0..511
    const int ls  = tid & 63;
    const int w   = tid >> 6;

    const int base = (b << 12) + (g << 9) + tid;
    float mn = partial[base];
    #pragma unroll
    for (int e = 1; e < NE; ++e)
        mn = fminf(mn, partial[(e << 15) + base]);

    #pragma unroll
    for (int off = 32; off > 0; off >>= 1)
        mn += __shfl_down(mn, off, 64);

    __shared__ float red[8];
    if (ls == 0) red[w] = mn;
    __syncthreads();
    if (tid == 0) {
        float s = 0.0f;
        #pragma unroll
        for (int k = 0; k < 8; ++k) s += red[k];
        atomicAdd(&out[b], s * (1.0f / (3.0f * (float)N_)));
    }
}

extern "C" void kernel_launch(void* const* d_in, const int* in_sizes, int n_in,
                              void* d_out, int out_size, void* d_ws, size_t ws_size,
                              hipStream_t stream) {
    const float* src = (const float*)d_in[0];   // [8,3,4096]
    const float* tgt = (const float*)d_in[1];   // [8,3,4096]
    float* out = (float*)d_out;                 // [8]
    float* partial = (float*)d_ws;              // 16*8*4096 floats = 2 MB

    hipMemsetAsync(out, 0, B_ * sizeof(float), stream);
    nn_loss_main<<<1024, 512, 0, stream>>>(src, tgt, partial);
    reduce_kernel<<<64, 512, 0, stream>>>(partial, out);
}

// Round 3
// 68.246 us; speedup vs baseline: 1.6417x; 1.0257x over previous
//
#include <hip/hip_runtime.h>

// KDPointToPointLoss: B=8, C=3, N=M=4096, fp32.
// loss[b] = (1/(3N)) * sum_n [ s_n^2 + min_m (t_m^2 - 2 s_n . t_m) ]
//
// R8: same two-phase structure as R7 (1024 blocks, TQ=256, 8 src/lane —
// VALU-bound ratio: LDS 12.3K cyc/CU < VALU 14.3K cyc/SIMD), three fixes:
//  - source prologue vectorized: lane owns 8 CONSECUTIVE sources, loaded
//    as 6 x global_load_dwordx4 (was 24 scalar dwords -> 4x fewer VMEM
//    issues, same bytes, coalesced 2KB/wave/row).
//  - memset dispatch dropped: main block 0 zeroes out[]; reduce's
//    atomicAdds run strictly after main (stream order).
//  - reduce: 128 blocks x 256 thr (was 64x512) -> half the loads/thread,
//    2x blocks for latency hiding.
// Remaining ~40us top dispatch is the harness's 256 MiB poison fill
// (fixed cost, evicts L2/L3 every iteration).

#define B_ 8
#define N_ 4096
#define CH 4096
#define BS 12288
#define TQ 256           // targets per block (one sixteenth)
#define NE 16            // target sixteenths
#define BIG 3.4e38f

__global__ __launch_bounds__(512, 8)    // 8 waves/EU -> 4 blocks/CU, VGPR<=64
void nn_loss_main(const float* __restrict__ src,
                  const float* __restrict__ tgt,
                  float* __restrict__ partial,
                  float* __restrict__ out) {
    __shared__ __align__(16) char smem[8 * 512 * 4];   // 16 KB: stage(4K), red(16K)
    float4* stage = (float4*)smem;
    float*  red   = (float*)smem;

    const int tid  = threadIdx.x;        // 0..511
    const int blk  = blockIdx.x;         // 0..1023
    const int b    = blk >> 7;           // 0..7
    const int e    = (blk >> 3) & 15;    // target sixteenth 0..15
    const int sgrp = blk & 7;            // source group 0..7 (512 srcs each)
    const int ls   = tid & 63;
    const int w    = tid >> 6;           // wave 0..7

    // zero the output accumulators (consumed by reduce_kernel's atomics,
    // which run strictly after this kernel retires)
    if (blk == 0 && tid < B_) out[tid] = 0.0f;

    // ---- vectorized source loads: lane owns 8 consecutive sources ----
    // all 8 waves load the SAME 512 sources (each wave sweeps different
    // targets); L1/L2 broadcast absorbs the redundancy.
    const float* sb = src + b * BS + (sgrp << 9);
    const float4* sx4 = (const float4*)sb;
    const float4* sy4 = (const float4*)(sb + CH);
    const float4* sz4 = (const float4*)(sb + 2 * CH);
    float4 x0 = sx4[ls * 2], x1 = sx4[ls * 2 + 1];
    float4 y0 = sy4[ls * 2], y1 = sy4[ls * 2 + 1];
    float4 z0 = sz4[ls * 2], z1 = sz4[ls * 2 + 1];

    // ---- stage this sixteenth's targets: (x,y,z, x^2+y^2+z^2) ----
    if (tid < TQ) {
        const float* tb = tgt + b * BS;
        const int m = (e << 8) + tid;
        float x = tb[m], y = tb[m + CH], z = tb[m + 2 * CH];
        stage[tid] = make_float4(x, y, z, x * x + y * y + z * z);
    }

    // unpack (store -2*coords; s^2 recomputed from these later)
    float ax[8], ay[8], az[8];
    ax[0] = -2.0f * x0.x; ax[1] = -2.0f * x0.y; ax[2] = -2.0f * x0.z; ax[3] = -2.0f * x0.w;
    ax[4] = -2.0f * x1.x; ax[5] = -2.0f * x1.y; ax[6] = -2.0f * x1.z; ax[7] = -2.0f * x1.w;
    ay[0] = -2.0f * y0.x; ay[1] = -2.0f * y0.y; ay[2] = -2.0f * y0.z; ay[3] = -2.0f * y0.w;
    ay[4] = -2.0f * y1.x; ay[5] = -2.0f * y1.y; ay[6] = -2.0f * y1.z; ay[7] = -2.0f * y1.w;
    az[0] = -2.0f * z0.x; az[1] = -2.0f * z0.y; az[2] = -2.0f * z0.z; az[3] = -2.0f * z0.w;
    az[4] = -2.0f * z1.x; az[5] = -2.0f * z1.y; az[6] = -2.0f * z1.z; az[7] = -2.0f * z1.w;

    __syncthreads();

    // ---- sweep this wave's 32 targets against 512 sources ----
    float best[8];
    #pragma unroll
    for (int j = 0; j < 8; ++j) best[j] = BIG;

    const float4* tp = stage + (w << 5);
    #pragma unroll 2
    for (int i = 0; i < 32; i += 2) {
        float4 t0 = tp[i];
        float4 t1 = tp[i + 1];
        #pragma unroll
        for (int j = 0; j < 8; ++j) {
            float d0 = fmaf(ax[j], t0.x, fmaf(ay[j], t0.y, fmaf(az[j], t0.z, t0.w)));
            float d1 = fmaf(ax[j], t1.x, fmaf(ay[j], t1.y, fmaf(az[j], t1.z, t1.w)));
            best[j] = fminf(fminf(best[j], d0), d1);   // v_min3_f32
        }
    }

    __syncthreads();   // staging reads done; reuse smem as red[8][512]

    // store best + s^2  (s^2 = 0.25*(ax^2+ay^2+az^2), exact pow2 scale)
    // lane (w,ls) slot j holds source (ls<<3)+j  -> bijective over 0..511
    #pragma unroll
    for (int j = 0; j < 8; ++j) {
        float s2 = 0.25f * fmaf(ax[j], ax[j], fmaf(ay[j], ay[j], az[j] * az[j]));
        red[(w << 9) + (ls << 3) + j] = best[j] + s2;
    }

    __syncthreads();

    // combine across 8 waves; thread tid handles source sgrp*512+tid
    float mn = red[tid];
    #pragma unroll
    for (int v = 1; v < 8; ++v)
        mn = fminf(mn, red[(v << 9) + tid]);
    partial[(e << 15) + (b << 12) + (sgrp << 9) + tid] = mn;
}

// ---- pass 2: min over 16 sixteenths per source, sum per batch ----
// 128 blocks = 8 batches x 16 source-chunks of 256; atomicAdd into out[].
__global__ __launch_bounds__(256)
void reduce_kernel(const float* __restrict__ partial,
                   float* __restrict__ out) {
    const int blk = blockIdx.x;          // 0..127
    const int b   = blk >> 4;            // batch
    const int c   = blk & 15;            // source chunk of 256
    const int tid = threadIdx.x;         // 0..255
    const int ls  = tid & 63;
    const int w   = tid >> 6;

    const int base = (b << 12) + (c << 8) + tid;
    float mn = partial[base];
    #pragma unroll
    for (int e = 1; e < NE; ++e)
        mn = fminf(mn, partial[(e << 15) + base]);

    #pragma unroll
    for (int off = 32; off > 0; off >>= 1)
        mn += __shfl_down(mn, off, 64);

    __shared__ float red[4];
    if (ls == 0) red[w] = mn;
    __syncthreads();
    if (tid == 0) {
        float s = (red[0] + red[1]) + (red[2] + red[3]);
        atomicAdd(&out[b], s * (1.0f / (3.0f * (float)N_)));
    }
}

extern "C" void kernel_launch(void* const* d_in, const int* in_sizes, int n_in,
                              void* d_out, int out_size, void* d_ws, size_t ws_size,
                              hipStream_t stream) {
    const float* src = (const float*)d_in[0];   // [8,3,4096]
    const float* tgt = (const float*)d_in[1];   // [8,3,4096]
    float* out = (float*)d_out;                 // [8]
    float* partial = (float*)d_ws;              // 16*8*4096 floats = 2 MB

    nn_loss_main<<<1024, 512, 0, stream>>>(src, tgt, partial, out);
    reduce_kernel<<<128, 256, 0, stream>>>(partial, out);
}

// Round 4
// 67.833 us; speedup vs baseline: 1.6517x; 1.0061x over previous
//
#include <hip/hip_runtime.h>

// KDPointToPointLoss: B=8, C=3, N=M=4096, fp32.
// loss[b] = (1/(3N)) * sum_n [ s_n^2 + min_m (t_m^2 - 2 s_n . t_m) ]
//
// R9: register-unthrottle experiment. Evidence: R6's counter row showed
// VGPR_Count=28 for a kernel whose live state is >=40 floats
// (ax/ay/az[8]+best[8]+t0/t1) -- __launch_bounds__(512,8) pinned the
// allocator and forced remat/reload in the sweep loop. That explains
// main ~20us vs its ~6us pipe floor (524K pairs/CU x 3.5 ops / 128
// lanes/cyc = 14.3K cyc VALU, 12.3K cyc LDS broadcast, overlapped) and
// why R5/R7/R8 restructures all landed ~68us. Fix: bounds (512,4)
// (<=128 VGPR budget; expect ~56-64 used). Pipe model says 4 waves/SIMD
// with 16 independent FMA chains/lane is enough to cover both pipes.
// Shape: back to R5's grid 512 = 8b x 8 target-eighths x 8 src-groups
// (TQ=512, 64 targets/wave -- best prologue amortization), with R8's
// vectorized source prologue. Reduce: 128 blocks, 8-deep min (NE=8).
// The ~40us top dispatch is the harness's 256 MiB workspace poison fill.

#define B_ 8
#define N_ 4096
#define CH 4096
#define BS 12288
#define TQ 512           // targets per block (one eighth)
#define NE 8             // target eighths
#define BIG 3.4e38f

__global__ __launch_bounds__(512, 4)    // >=4 waves/EU; VGPR budget 128
void nn_loss_main(const float* __restrict__ src,
                  const float* __restrict__ tgt,
                  float* __restrict__ partial,
                  float* __restrict__ out) {
    __shared__ __align__(16) char smem[8 * TQ * 4];   // 16 KB: stage(8K), red(16K)
    float4* stage = (float4*)smem;
    float*  red   = (float*)smem;

    const int tid  = threadIdx.x;        // 0..511
    const int blk  = blockIdx.x;         // 0..511
    const int b    = blk >> 6;           // 0..7
    const int e    = (blk >> 3) & 7;     // target eighth 0..7
    const int sgrp = blk & 7;            // source group 0..7 (512 srcs each)
    const int ls   = tid & 63;
    const int w    = tid >> 6;           // wave 0..7

    // zero the output accumulators (consumed by reduce_kernel's atomics,
    // which run strictly after this kernel retires)
    if (blk == 0 && tid < B_) out[tid] = 0.0f;

    // ---- stage this eighth's targets: (x,y,z, x^2+y^2+z^2) ----
    {
        const float* tb = tgt + b * BS;
        const int m = (e << 9) + tid;
        float x = tb[m], y = tb[m + CH], z = tb[m + 2 * CH];
        stage[tid] = make_float4(x, y, z, x * x + y * y + z * z);
    }

    // ---- vectorized source loads: lane owns 8 consecutive sources ----
    const float* sb = src + b * BS + (sgrp << 9);
    const float4* sx4 = (const float4*)sb;
    const float4* sy4 = (const float4*)(sb + CH);
    const float4* sz4 = (const float4*)(sb + 2 * CH);
    float4 x0 = sx4[ls * 2], x1 = sx4[ls * 2 + 1];
    float4 y0 = sy4[ls * 2], y1 = sy4[ls * 2 + 1];
    float4 z0 = sz4[ls * 2], z1 = sz4[ls * 2 + 1];

    // unpack (store -2*coords; s^2 recomputed from these later)
    float ax[8], ay[8], az[8];
    ax[0] = -2.0f * x0.x; ax[1] = -2.0f * x0.y; ax[2] = -2.0f * x0.z; ax[3] = -2.0f * x0.w;
    ax[4] = -2.0f * x1.x; ax[5] = -2.0f * x1.y; ax[6] = -2.0f * x1.z; ax[7] = -2.0f * x1.w;
    ay[0] = -2.0f * y0.x; ay[1] = -2.0f * y0.y; ay[2] = -2.0f * y0.z; ay[3] = -2.0f * y0.w;
    ay[4] = -2.0f * y1.x; ay[5] = -2.0f * y1.y; ay[6] = -2.0f * y1.z; ay[7] = -2.0f * y1.w;
    az[0] = -2.0f * z0.x; az[1] = -2.0f * z0.y; az[2] = -2.0f * z0.z; az[3] = -2.0f * z0.w;
    az[4] = -2.0f * z1.x; az[5] = -2.0f * z1.y; az[6] = -2.0f * z1.z; az[7] = -2.0f * z1.w;

    __syncthreads();

    // ---- sweep this wave's 64 targets against 512 sources ----
    float best[8];
    #pragma unroll
    for (int j = 0; j < 8; ++j) best[j] = BIG;

    const float4* tp = stage + (w << 6);
    #pragma unroll 2
    for (int i = 0; i < 64; i += 2) {
        float4 t0 = tp[i];
        float4 t1 = tp[i + 1];
        #pragma unroll
        for (int j = 0; j < 8; ++j) {
            float d0 = fmaf(ax[j], t0.x, fmaf(ay[j], t0.y, fmaf(az[j], t0.z, t0.w)));
            float d1 = fmaf(ax[j], t1.x, fmaf(ay[j], t1.y, fmaf(az[j], t1.z, t1.w)));
            best[j] = fminf(fminf(best[j], d0), d1);   // v_min3_f32
        }
    }

    __syncthreads();   // staging reads done; reuse smem as red[8][512]

    // store best + s^2  (s^2 = 0.25*(ax^2+ay^2+az^2), exact pow2 scale)
    // lane (w,ls) slot j holds source (ls<<3)+j  -> bijective over 0..511
    #pragma unroll
    for (int j = 0; j < 8; ++j) {
        float s2 = 0.25f * fmaf(ax[j], ax[j], fmaf(ay[j], ay[j], az[j] * az[j]));
        red[(w << 9) + (ls << 3) + j] = best[j] + s2;
    }

    __syncthreads();

    // combine across 8 waves; thread tid handles source sgrp*512+tid
    float mn = red[tid];
    #pragma unroll
    for (int v = 1; v < 8; ++v)
        mn = fminf(mn, red[(v << 9) + tid]);
    partial[(e << 15) + (b << 12) + (sgrp << 9) + tid] = mn;
}

// ---- pass 2: min over 8 eighths per source, sum per batch ----
// 128 blocks = 8 batches x 16 source-chunks of 256; atomicAdd into out[].
__global__ __launch_bounds__(256)
void reduce_kernel(const float* __restrict__ partial,
                   float* __restrict__ out) {
    const int blk = blockIdx.x;          // 0..127
    const int b   = blk >> 4;            // batch
    const int c   = blk & 15;            // source chunk of 256
    const int tid = threadIdx.x;         // 0..255
    const int ls  = tid & 63;
    const int w   = tid >> 6;

    const int base = (b << 12) + (c << 8) + tid;
    float mn = partial[base];
    #pragma unroll
    for (int e = 1; e < NE; ++e)
        mn = fminf(mn, partial[(e << 15) + base]);

    #pragma unroll
    for (int off = 32; off > 0; off >>= 1)
        mn += __shfl_down(mn, off, 64);

    __shared__ float red[4];
    if (ls == 0) red[w] = mn;
    __syncthreads();
    if (tid == 0) {
        float s = (red[0] + red[1]) + (red[2] + red[3]);
        atomicAdd(&out[b], s * (1.0f / (3.0f * (float)N_)));
    }
}

extern "C" void kernel_launch(void* const* d_in, const int* in_sizes, int n_in,
                              void* d_out, int out_size, void* d_ws, size_t ws_size,
                              hipStream_t stream) {
    const float* src = (const float*)d_in[0];   // [8,3,4096]
    const float* tgt = (const float*)d_in[1];   // [8,3,4096]
    float* out = (float*)d_out;                 // [8]
    float* partial = (float*)d_ws;              // 8*8*4096 floats = 1 MB

    nn_loss_main<<<512, 512, 0, stream>>>(src, tgt, partial, out);
    reduce_kernel<<<128, 256, 0, stream>>>(partial, out);
}

// Round 5
// 67.487 us; speedup vs baseline: 1.6602x; 1.0051x over previous
//
#include <hip/hip_runtime.h>

// KDPointToPointLoss: B=8, C=3, N=M=4096, fp32.
// loss[b] = (1/(3N)) * sum_n [ s_n^2 + min_m (t_m^2 - 2 s_n . t_m) ]
//
// R10: packed-FP32 inner loop. Evidence: R6's VALUBusy (24.8% x 46.5us
// = 11.5us VALU-issue) shows main is VALU-issue-bound; the scalar loop
// is 3.5 inst/pair (3 fma + min3/2). gfx950 has v_pk_fma_f32 (VOP3P);
// the 64-bit-per-lane datapath (FP64 vector = same inst rate as FP32)
// implies pk executes 2 FMAs/issue. Pack TARGETS in pairs:
//   per target-pair, per source: 3 v_pk_fma_f32 + 1 v_min3_f32
//   -> 2.0 inst/pair, source broadcast pairs hoisted to prologue.
// LDS restaged as (x0,x1,y0,y1)(z0,z1,w0,w1) per target-pair so packed
// operands come straight from ds_read_b128 (uniform-addr broadcast,
// 0 conflicts, same 2 reads per target-pair as R9).
// Discriminating experiment: pk full-rate -> main -4..6us (dur ~62-64);
// pk half-rate -> unchanged (~68) and next lever is dispatch fusion.
// Shape/reduce unchanged from R9. Top dispatch remains the harness's
// 256 MiB workspace poison fill (~40us, itself at HBM roofline).

#define B_ 8
#define N_ 4096
#define CH 4096
#define BS 12288
#define TQ 512           // targets per block (one eighth)
#define NE 8             // target eighths
#define BIG 3.4e38f

typedef float v2f __attribute__((ext_vector_type(2)));
typedef float v4f __attribute__((ext_vector_type(4)));

__device__ __forceinline__ v2f pk_fma(v2f a, v2f b, v2f c) {
    v2f d;
    asm("v_pk_fma_f32 %0, %1, %2, %3" : "=v"(d) : "v"(a), "v"(b), "v"(c));
    return d;
}

__global__ __launch_bounds__(512, 4)    // VGPR budget 128
void nn_loss_main(const float* __restrict__ src,
                  const float* __restrict__ tgt,
                  float* __restrict__ partial,
                  float* __restrict__ out) {
    __shared__ __align__(16) char smem[8 * TQ * 4];   // 16 KB: stage(8K), red(16K)
    v4f*   stage = (v4f*)smem;
    float* red   = (float*)smem;

    const int tid  = threadIdx.x;        // 0..511
    const int blk  = blockIdx.x;         // 0..511
    const int b    = blk >> 6;           // 0..7
    const int e    = (blk >> 3) & 7;     // target eighth 0..7
    const int sgrp = blk & 7;            // source group 0..7 (512 srcs each)
    const int ls   = tid & 63;
    const int w    = tid >> 6;           // wave 0..7

    // zero the output accumulators (consumed by reduce_kernel's atomics,
    // which run strictly after this kernel retires)
    if (blk == 0 && tid < B_) out[tid] = 0.0f;

    // ---- stage this eighth's targets in PAIR layout ----
    // pair p: stage[2p] = (x0,x1,y0,y1), stage[2p+1] = (z0,z1,w0,w1),
    // w = x^2+y^2+z^2. Thread p (0..255) stages targets 2p, 2p+1.
    if (tid < 256) {
        const float* tb = tgt + b * BS + (e << 9) + 2 * tid;
        v2f X = *(const v2f*)(tb);
        v2f Y = *(const v2f*)(tb + CH);
        v2f Z = *(const v2f*)(tb + 2 * CH);
        v2f W = X * X + Y * Y + Z * Z;
        stage[2 * tid]     = (v4f){X.x, X.y, Y.x, Y.y};
        stage[2 * tid + 1] = (v4f){Z.x, Z.y, W.x, W.y};
    }

    // ---- vectorized source loads: lane owns 8 consecutive sources ----
    const float* sb = src + b * BS + (sgrp << 9);
    const float4* sx4 = (const float4*)sb;
    const float4* sy4 = (const float4*)(sb + CH);
    const float4* sz4 = (const float4*)(sb + 2 * CH);
    float4 x0 = sx4[ls * 2], x1 = sx4[ls * 2 + 1];
    float4 y0 = sy4[ls * 2], y1 = sy4[ls * 2 + 1];
    float4 z0 = sz4[ls * 2], z1 = sz4[ls * 2 + 1];

    // broadcast pairs of -2*coord (loop-invariant pk operands)
    v2f ax2[8], ay2[8], az2[8];
    {
        float t;
        t = -2.0f * x0.x; ax2[0] = (v2f){t, t};
        t = -2.0f * x0.y; ax2[1] = (v2f){t, t};
        t = -2.0f * x0.z; ax2[2] = (v2f){t, t};
        t = -2.0f * x0.w; ax2[3] = (v2f){t, t};
        t = -2.0f * x1.x; ax2[4] = (v2f){t, t};
        t = -2.0f * x1.y; ax2[5] = (v2f){t, t};
        t = -2.0f * x1.z; ax2[6] = (v2f){t, t};
        t = -2.0f * x1.w; ax2[7] = (v2f){t, t};
        t = -2.0f * y0.x; ay2[0] = (v2f){t, t};
        t = -2.0f * y0.y; ay2[1] = (v2f){t, t};
        t = -2.0f * y0.z; ay2[2] = (v2f){t, t};
        t = -2.0f * y0.w; ay2[3] = (v2f){t, t};
        t = -2.0f * y1.x; ay2[4] = (v2f){t, t};
        t = -2.0f * y1.y; ay2[5] = (v2f){t, t};
        t = -2.0f * y1.z; ay2[6] = (v2f){t, t};
        t = -2.0f * y1.w; ay2[7] = (v2f){t, t};
        t = -2.0f * z0.x; az2[0] = (v2f){t, t};
        t = -2.0f * z0.y; az2[1] = (v2f){t, t};
        t = -2.0f * z0.z; az2[2] = (v2f){t, t};
        t = -2.0f * z0.w; az2[3] = (v2f){t, t};
        t = -2.0f * z1.x; az2[4] = (v2f){t, t};
        t = -2.0f * z1.y; az2[5] = (v2f){t, t};
        t = -2.0f * z1.z; az2[6] = (v2f){t, t};
        t = -2.0f * z1.w; az2[7] = (v2f){t, t};
    }

    __syncthreads();

    // ---- sweep this wave's 64 targets (32 pairs) against 512 sources ----
    float best[8];
    #pragma unroll
    for (int j = 0; j < 8; ++j) best[j] = BIG;

    const v4f* tp = stage + (w << 6);    // 64 v4f = 32 target-pairs
    #pragma unroll 2
    for (int i = 0; i < 32; ++i) {
        v4f P = tp[2 * i];               // (x0,x1,y0,y1)
        v4f Q = tp[2 * i + 1];           // (z0,z1,w0,w1)
        v2f xx = __builtin_shufflevector(P, P, 0, 1);
        v2f yy = __builtin_shufflevector(P, P, 2, 3);
        v2f zz = __builtin_shufflevector(Q, Q, 0, 1);
        v2f ww = __builtin_shufflevector(Q, Q, 2, 3);
        #pragma unroll
        for (int j = 0; j < 8; ++j) {
            v2f d2 = pk_fma(az2[j], zz, ww);
            d2 = pk_fma(ay2[j], yy, d2);
            d2 = pk_fma(ax2[j], xx, d2);
            best[j] = fminf(fminf(best[j], d2.x), d2.y);   // v_min3_f32
        }
    }

    __syncthreads();   // staging reads done; reuse smem as red[8][512]

    // store best + s^2  (s^2 = 0.25*(ax^2+ay^2+az^2), exact pow2 scale)
    // lane (w,ls) slot j holds source (ls<<3)+j  -> bijective over 0..511
    #pragma unroll
    for (int j = 0; j < 8; ++j) {
        float axs = ax2[j].x, ays = ay2[j].x, azs = az2[j].x;
        float s2 = 0.25f * fmaf(axs, axs, fmaf(ays, ays, azs * azs));
        red[(w << 9) + (ls << 3) + j] = best[j] + s2;
    }

    __syncthreads();

    // combine across 8 waves; thread tid handles source sgrp*512+tid
    float mn = red[tid];
    #pragma unroll
    for (int v = 1; v < 8; ++v)
        mn = fminf(mn, red[(v << 9) + tid]);
    partial[(e << 15) + (b << 12) + (sgrp << 9) + tid] = mn;
}

// ---- pass 2: min over 8 eighths per source, sum per batch ----
// 128 blocks = 8 batches x 16 source-chunks of 256; atomicAdd into out[].
__global__ __launch_bounds__(256)
void reduce_kernel(const float* __restrict__ partial,
                   float* __restrict__ out) {
    const int blk = blockIdx.x;          // 0..127
    const int b   = blk >> 4;            // batch
    const int c   = blk & 15;            // source chunk of 256
    const int tid = threadIdx.x;         // 0..255
    const int ls  = tid & 63;
    const int w   = tid >> 6;

    const int base = (b << 12) + (c << 8) + tid;
    float mn = partial[base];
    #pragma unroll
    for (int e = 1; e < NE; ++e)
        mn = fminf(mn, partial[(e << 15) + base]);

    #pragma unroll
    for (int off = 32; off > 0; off >>= 1)
        mn += __shfl_down(mn, off, 64);

    __shared__ float red[4];
    if (ls == 0) red[w] = mn;
    __syncthreads();
    if (tid == 0) {
        float s = (red[0] + red[1]) + (red[2] + red[3]);
        atomicAdd(&out[b], s * (1.0f / (3.0f * (float)N_)));
    }
}

extern "C" void kernel_launch(void* const* d_in, const int* in_sizes, int n_in,
                              void* d_out, int out_size, void* d_ws, size_t ws_size,
                              hipStream_t stream) {
    const float* src = (const float*)d_in[0];   // [8,3,4096]
    const float* tgt = (const float*)d_in[1];   // [8,3,4096]
    float* out = (float*)d_out;                 // [8]
    float* partial = (float*)d_ws;              // 8*8*4096 floats = 1 MB

    nn_loss_main<<<512, 512, 0, stream>>>(src, tgt, partial, out);
    reduce_kernel<<<128, 256, 0, stream>>>(partial, out);
}